// Round 12
// baseline (537.548 us; speedup 1.0000x reference)
//
#include <hip/hip_runtime.h>
#include <hip/hip_bf16.h>
#include <hip/hip_fp16.h>

// GCN 3-layer forward.
// CSR build (count -> fused dinv+alloc -> fill -> per-row source SORT) -> per layer:
//   asymmetric fp16 MFMA GEMM (A: 1 fp16 plane; W: fp16 hi+lo; 2 MFMAs; global->reg prefetch)
//   -> CSR agg over fp16 rows (8-deep gather pipeline, BN/ReLU, fp16 plane out).
// Round-11 counters: agg FETCH = 8 XCD x full fp16 matrix (187MB) -- every XCD streams the
// whole matrix through its 4MB L2. Sorted per-row sources => concurrent waves walk a shared
// sliding source window => L2-resident working set. Sum-order change only (fp32 accum).

#define GN 50000
#define GE 800000

typedef float f32x4 __attribute__((ext_vector_type(4)));
typedef _Float16 f16x8 __attribute__((ext_vector_type(8)));

// ---------------- graph setup ----------------

__global__ __launch_bounds__(256) void init_kernel(int* counts, int* cursor, int* total) {
    int i = blockIdx.x * 256 + threadIdx.x;
    if (i < GN) { counts[i] = 0; cursor[i] = 0; }
    if (i == 0) *total = 0;
}

__global__ __launch_bounds__(256) void count_kernel(const int* __restrict__ dst, int* __restrict__ counts) {
    int e = blockIdx.x * 256 + threadIdx.x;
    if (e < GE) atomicAdd(&counts[dst[e]], 1);
}

// fused: dinv + disjoint CSR segment allocation (wave shfl-scan + 1 atomic/wave)
__global__ __launch_bounds__(256) void alloc_kernel(const int* __restrict__ counts, float* __restrict__ dinv,
                                                    int* __restrict__ base, int* __restrict__ total) {
    int i = blockIdx.x * 256 + threadIdx.x;
    int lane = threadIdx.x & 63;
    int c = (i < GN) ? counts[i] : 0;
    if (i < GN) dinv[i] = rsqrtf((float)c + 1.0f);
    int v = c;
#pragma unroll
    for (int off = 1; off < 64; off <<= 1) {
        int t = __shfl_up(v, off);
        if (lane >= off) v += t;
    }
    int waveSum = __shfl(v, 63);
    int wb = 0;
    if (lane == 63) wb = atomicAdd(total, waveSum);
    wb = __shfl(wb, 63);
    if (i < GN) base[i] = wb + v - c;  // exclusive intra-wave prefix + wave base
}

__global__ __launch_bounds__(256) void fill_kernel(const int* __restrict__ src, const int* __restrict__ dst,
                                                   const int* __restrict__ base, int* __restrict__ cursor,
                                                   int* __restrict__ col) {
    int e = blockIdx.x * 256 + threadIdx.x;
    if (e < GE) {
        int d = dst[e];
        int pos = base[d] + atomicAdd(&cursor[d], 1);
        col[pos] = src[e];
    }
}

// per-row ascending insertion sort of column indices (avg degree 16; col rows contiguous, L2-resident)
__global__ __launch_bounds__(256) void sort_kernel(const int* __restrict__ base, const int* __restrict__ counts,
                                                   int* __restrict__ col) {
    int w = blockIdx.x * 256 + threadIdx.x;
    if (w >= GN) return;
    int b = base[w], n = counts[w];
    for (int i = 1; i < n; i++) {
        int key = col[b + i];
        int j = i - 1;
        while (j >= 0 && col[b + j] > key) { col[b + j + 1] = col[b + j]; j--; }
        col[b + j + 1] = key;
    }
}

__global__ __launch_bounds__(256) void params_kernel(
    const float* b1, const float* g1, const float* be1, const float* m1, const float* v1,
    const float* b2, const float* g2, const float* be2, const float* m2, const float* v2,
    float* prm) {
    int t = threadIdx.x;
    float s1 = g1[t] * rsqrtf(v1[t] + 1e-5f);
    prm[0 * 256 + t] = s1;
    prm[1 * 256 + t] = (b1[t] - m1[t]) * s1 + be1[t];
    float s2 = g2[t] * rsqrtf(v2[t] + 1e-5f);
    prm[2 * 256 + t] = s2;
    prm[3 * 256 + t] = (b2[t] - m2[t]) * s2 + be2[t];
}

// ---------------- pre-passes ----------------

// x fp32 -> single fp16 plane
__global__ __launch_bounds__(256) void conv_x(const float* __restrict__ in, ushort* __restrict__ out, int n4) {
    int i = blockIdx.x * 256 + threadIdx.x;
    if (i >= n4) return;
    float4 v = *(const float4*)&in[(size_t)i * 4];
    ushort4 h;
    h.x = __half_as_ushort(__float2half_rn(v.x));
    h.y = __half_as_ushort(__float2half_rn(v.y));
    h.z = __half_as_ushort(__float2half_rn(v.z));
    h.w = __half_as_ushort(__float2half_rn(v.w));
    *(ushort4*)&out[(size_t)i * 4] = h;
}

// all three W [256][DO] fp32 -> WT hi/lo fp16 [DO][256], one kernel
__global__ __launch_bounds__(256) void transpose_all(const float* __restrict__ W1, const float* __restrict__ W2,
                                                     const float* __restrict__ W3,
                                                     ushort* __restrict__ T1h, ushort* __restrict__ T1l,
                                                     ushort* __restrict__ T2h, ushort* __restrict__ T2l,
                                                     ushort* __restrict__ T3h, ushort* __restrict__ T3l) {
    int idx = blockIdx.x * 256 + threadIdx.x;
    const float* W;
    ushort *Th, *Tl;
    int i, DO;
    if (idx < 65536) { W = W1; Th = T1h; Tl = T1l; i = idx; DO = 256; }
    else if (idx < 131072) { W = W2; Th = T2h; Tl = T2l; i = idx - 65536; DO = 256; }
    else if (idx < 163840) { W = W3; Th = T3h; Tl = T3l; i = idx - 131072; DO = 128; }
    else return;
    int n = i >> 8, k = i & 255;
    float v = W[k * DO + n];
    __half h = __float2half_rn(v);
    Th[i] = __half_as_ushort(h);
    Tl[i] = __half_as_ushort(__float2half_rn(v - __half2float(h)));
}

// ---------------- asymmetric fp16 MFMA GEMM with global->reg prefetch ----------------
// C[m][n] = dinv[m] * sum_k A[m][k]*W[k][n]; A: fp16 plane [M][256];
// W: transposed fp16 hi/lo planes [DO][256]. BM=128,BN=128,BK=32; 4 waves (2x2), 64x64/wave.

template <int DO>
__global__ __launch_bounds__(256) void gemm_mfma(const ushort* __restrict__ A16, const ushort* __restrict__ Bhi,
                                                 const ushort* __restrict__ Blo, const float* __restrict__ dinv,
                                                 __half* __restrict__ C, int M) {
    __shared__ ushort lds[3][128][40];  // 80B rows (pad 16B) -> <=2-way bank conflict on ds_read_b128
    int tid = threadIdx.x;
    int lane = tid & 63;
    int wave = tid >> 6;
    int wm = wave >> 1, wn = wave & 1;
    int m0 = blockIdx.x * 128;
    int n0 = blockIdx.y * 128;
    int rsel = lane & 15;
    int ksel = (lane >> 4) * 8;

    // staging coordinates (2 x 16B per plane per thread)
    int o0 = tid * 16, o1 = (tid + 256) * 16;
    int row0 = o0 >> 6, kb0 = o0 & 63;
    int row1 = o1 >> 6, kb1 = o1 & 63;
    int rA0 = min(m0 + row0, M - 1), rA1 = min(m0 + row1, M - 1);
    int rB0 = min(n0 + row0, DO - 1), rB1 = min(n0 + row1, DO - 1);

    uint4 vA0, vA1, vBh0, vBh1, vBl0, vBl1;
    auto loadregs = [&](int k0) {
        const char* a = (const char*)A16;
        const char* bh = (const char*)Bhi;
        const char* bl = (const char*)Blo;
        vA0 = *(const uint4*)(a + (size_t)rA0 * 512 + (size_t)k0 * 2 + kb0);
        vA1 = *(const uint4*)(a + (size_t)rA1 * 512 + (size_t)k0 * 2 + kb1);
        vBh0 = *(const uint4*)(bh + (size_t)rB0 * 512 + (size_t)k0 * 2 + kb0);
        vBh1 = *(const uint4*)(bh + (size_t)rB1 * 512 + (size_t)k0 * 2 + kb1);
        vBl0 = *(const uint4*)(bl + (size_t)rB0 * 512 + (size_t)k0 * 2 + kb0);
        vBl1 = *(const uint4*)(bl + (size_t)rB1 * 512 + (size_t)k0 * 2 + kb1);
    };
    auto writelds = [&]() {
        *(uint4*)((char*)&lds[0][row0][0] + kb0) = vA0;
        *(uint4*)((char*)&lds[0][row1][0] + kb1) = vA1;
        *(uint4*)((char*)&lds[1][row0][0] + kb0) = vBh0;
        *(uint4*)((char*)&lds[1][row1][0] + kb1) = vBh1;
        *(uint4*)((char*)&lds[2][row0][0] + kb0) = vBl0;
        *(uint4*)((char*)&lds[2][row1][0] + kb1) = vBl1;
    };

    f32x4 acc[4][4] = {};

    loadregs(0);
    for (int k0 = 0; k0 < 256; k0 += 32) {
        writelds();
        __syncthreads();
        if (k0 + 32 < 256) loadregs(k0 + 32);  // prefetch next K-step; HBM latency hides under MFMA

        f16x8 bh[4], bl[4];
#pragma unroll
        for (int ni = 0; ni < 4; ni++) {
            bh[ni] = *(const f16x8*)&lds[1][wn * 64 + ni * 16 + rsel][ksel];
            bl[ni] = *(const f16x8*)&lds[2][wn * 64 + ni * 16 + rsel][ksel];
        }
#pragma unroll
        for (int mi = 0; mi < 4; mi++) {
            f16x8 av = *(const f16x8*)&lds[0][wm * 64 + mi * 16 + rsel][ksel];
#pragma unroll
            for (int ni = 0; ni < 4; ni++) {
                acc[mi][ni] = __builtin_amdgcn_mfma_f32_16x16x32_f16(av, bh[ni], acc[mi][ni], 0, 0, 0);
                acc[mi][ni] = __builtin_amdgcn_mfma_f32_16x16x32_f16(av, bl[ni], acc[mi][ni], 0, 0, 0);
            }
        }
        __syncthreads();
    }

    // epilogue: C/D layout col=lane&15, row=(lane>>4)*4+j  [m89-verified]; fp16 store
#pragma unroll
    for (int mi = 0; mi < 4; mi++) {
#pragma unroll
        for (int j = 0; j < 4; j++) {
            int r = m0 + wm * 64 + mi * 16 + (lane >> 4) * 4 + j;
            if (r < M) {
                float dv = dinv[r];
#pragma unroll
                for (int ni = 0; ni < 4; ni++) {
                    int c = n0 + wn * 64 + ni * 16 + rsel;
                    C[(size_t)r * DO + c] = __float2half_rn(acc[mi][ni][j] * dv);
                }
            }
        }
    }
}

// ---------------- CSR aggregation over fp16 rows (8-deep gather pipeline) ----------------
// MODE 1: val = relu(val*pa+pc), write fp16 plane. MODE 0: val = val + pa, write fp32.
template <int D, int MODE>
__global__ __launch_bounds__(256) void agg_kernel(const __half* __restrict__ Hs, const int* __restrict__ base,
                                                  const int* __restrict__ counts, const float* __restrict__ dinv,
                                                  const int* __restrict__ col,
                                                  const float* __restrict__ pa, const float* __restrict__ pc,
                                                  float* __restrict__ outF, ushort* __restrict__ outH, int M) {
    constexpr int V = D / 64;   // halfs per lane: 4 (D=256) or 2 (D=128)
    constexpr int P = V / 2;    // float2 accumulators
    int w = blockIdx.x * 4 + (threadIdx.x >> 6);
    if (w >= M) return;
    int lane = threadIdx.x & 63;
    const char* gbase = (const char*)(Hs + lane * V);  // + s*D*2 bytes per row
    float2 acc2[P];
#pragma unroll
    for (int j = 0; j < P; j++) acc2[j] = make_float2(0.f, 0.f);

    auto accum32 = [&](unsigned bits, int j2) {  // add 2 halfs packed in u32
        __half2 h = *(__half2*)&bits;
        float2 f = __half22float2(h);
        acc2[j2].x += f.x;
        acc2[j2].y += f.y;
    };

    // self loop
    if constexpr (V == 4) {
        uint2 r = *(const uint2*)(gbase + (size_t)w * D * 2);
        accum32(r.x, 0); accum32(r.y, 1);
    } else {
        unsigned r = *(const unsigned*)(gbase + (size_t)w * D * 2);
        accum32(r, 0);
    }

    int e = base[w], end = e + counts[w];
    // 8 rows in flight
    for (; e + 8 <= end; e += 8) {
        int idx[8];
#pragma unroll
        for (int t = 0; t < 8; t++) idx[t] = col[e + t];
        if constexpr (V == 4) {
            uint2 r[8];
#pragma unroll
            for (int t = 0; t < 8; t++) r[t] = *(const uint2*)(gbase + (size_t)idx[t] * (D * 2));
#pragma unroll
            for (int t = 0; t < 8; t++) { accum32(r[t].x, 0); accum32(r[t].y, 1); }
        } else {
            unsigned r[8];
#pragma unroll
            for (int t = 0; t < 8; t++) r[t] = *(const unsigned*)(gbase + (size_t)idx[t] * (D * 2));
#pragma unroll
            for (int t = 0; t < 8; t++) accum32(r[t], 0);
        }
    }
    for (; e < end; e++) {
        int s = col[e];
        if constexpr (V == 4) {
            uint2 r = *(const uint2*)(gbase + (size_t)s * (D * 2));
            accum32(r.x, 0); accum32(r.y, 1);
        } else {
            unsigned r = *(const unsigned*)(gbase + (size_t)s * (D * 2));
            accum32(r, 0);
        }
    }

    float dv = dinv[w];
    float acc[V];
#pragma unroll
    for (int j = 0; j < P; j++) { acc[2 * j] = acc2[j].x; acc[2 * j + 1] = acc2[j].y; }

    if constexpr (MODE == 1) {
        ushort4 h;
        int d = lane * V;
        float val;
        val = fmaxf(fmaf(acc[0] * dv, pa[d + 0], pc[d + 0]), 0.f);
        h.x = __half_as_ushort(__float2half_rn(val));
        val = fmaxf(fmaf(acc[1] * dv, pa[d + 1], pc[d + 1]), 0.f);
        h.y = __half_as_ushort(__float2half_rn(val));
        val = fmaxf(fmaf(acc[2] * dv, pa[d + 2], pc[d + 2]), 0.f);
        h.z = __half_as_ushort(__float2half_rn(val));
        val = fmaxf(fmaf(acc[3] * dv, pa[d + 3], pc[d + 3]), 0.f);
        h.w = __half_as_ushort(__float2half_rn(val));
        *(ushort4*)&outH[(size_t)w * D + d] = h;
    } else {
#pragma unroll
        for (int j = 0; j < V; j++) {
            int d = lane * V + j;
            outF[(size_t)w * D + d] = acc[j] * dv + pa[d];
        }
    }
}

// ---------------- launch ----------------

extern "C" void kernel_launch(void* const* d_in, const int* in_sizes, int n_in,
                              void* d_out, int out_size, void* d_ws, size_t ws_size,
                              hipStream_t stream) {
    const float* x = (const float*)d_in[0];
    const int* ei = (const int*)d_in[1];
    const int* srcIdx = ei;
    const int* dstIdx = ei + GE;
    const float* W1 = (const float*)d_in[2];
    const float* b1 = (const float*)d_in[3];
    const float* g1 = (const float*)d_in[4];
    const float* be1 = (const float*)d_in[5];
    const float* m1 = (const float*)d_in[6];
    const float* v1 = (const float*)d_in[7];
    const float* W2 = (const float*)d_in[8];
    const float* b2 = (const float*)d_in[9];
    const float* g2 = (const float*)d_in[10];
    const float* be2 = (const float*)d_in[11];
    const float* m2 = (const float*)d_in[12];
    const float* v2 = (const float*)d_in[13];
    const float* W3 = (const float*)d_in[14];
    const float* b3 = (const float*)d_in[15];
    float* out = (float*)d_out;

    size_t off = 0;
    char* wsb = (char*)d_ws;
    auto take = [&](size_t bytes) -> char* {
        char* p = wsb + off;
        off += (bytes + 255) & ~(size_t)255;
        return p;
    };
    float* dinv = (float*)take((size_t)GN * 4);
    int* counts = (int*)take((size_t)GN * 4);
    int* cursor = (int*)take((size_t)GN * 4);
    int* segbase = (int*)take((size_t)GN * 4);
    int* total = (int*)take(256);
    int* col = (int*)take((size_t)GE * 4);
    float* prm = (float*)take(4 * 256 * 4);
    __half* hH = (__half*)take((size_t)GN * 256 * 2);  // GEMM output (fp16)
    ushort* P = (ushort*)take((size_t)GN * 256 * 2);   // activation fp16 plane (x16 aliased)
    ushort* X16 = P;                                   // layer-1 A: fp16(x); consumed before agg writes P
    ushort* WT1h = (ushort*)take(256 * 256 * 2);
    ushort* WT1l = (ushort*)take(256 * 256 * 2);
    ushort* WT2h = (ushort*)take(256 * 256 * 2);
    ushort* WT2l = (ushort*)take(256 * 256 * 2);
    ushort* WT3h = (ushort*)take(128 * 256 * 2);
    ushort* WT3l = (ushort*)take(128 * 256 * 2);

    const float* a1 = prm + 0 * 256;
    const float* c1 = prm + 1 * 256;
    const float* a2 = prm + 2 * 256;
    const float* c2 = prm + 3 * 256;

    int nb = (GN + 255) / 256;
    int eb = (GE + 255) / 256;

    init_kernel<<<nb, 256, 0, stream>>>(counts, cursor, total);
    count_kernel<<<eb, 256, 0, stream>>>(dstIdx, counts);
    alloc_kernel<<<nb, 256, 0, stream>>>(counts, dinv, segbase, total);
    fill_kernel<<<eb, 256, 0, stream>>>(srcIdx, dstIdx, segbase, cursor, col);
    sort_kernel<<<nb, 256, 0, stream>>>(segbase, counts, col);
    params_kernel<<<1, 256, 0, stream>>>(b1, g1, be1, m1, v1, b2, g2, be2, m2, v2, prm);

    int n4 = GN * 64;  // GN*256/4 float4s
    conv_x<<<(n4 + 255) / 256, 256, 0, stream>>>(x, X16, n4);
    transpose_all<<<(163840 + 255) / 256, 256, 0, stream>>>(W1, W2, W3, WT1h, WT1l, WT2h, WT2l, WT3h, WT3l);

    dim3 gg((GN + 127) / 128, 2);
    dim3 gg3((GN + 127) / 128, 1);
    int ab = (GN + 3) / 4;

    // layer 1
    gemm_mfma<256><<<gg, 256, 0, stream>>>(X16, WT1h, WT1l, dinv, hH, GN);
    agg_kernel<256, 1><<<ab, 256, 0, stream>>>(hH, segbase, counts, dinv, col, a1, c1, nullptr, P, GN);
    // layer 2
    gemm_mfma<256><<<gg, 256, 0, stream>>>(P, WT2h, WT2l, dinv, hH, GN);
    agg_kernel<256, 1><<<ab, 256, 0, stream>>>(hH, segbase, counts, dinv, col, a2, c2, nullptr, P, GN);
    // layer 3
    gemm_mfma<128><<<gg3, 256, 0, stream>>>(P, WT3h, WT3l, dinv, hH, GN);
    agg_kernel<128, 0><<<ab, 256, 0, stream>>>(hH, segbase, counts, dinv, col, b3, b3, out, nullptr, GN);
}

// Round 13
// 440.656 us; speedup vs baseline: 1.2199x; 1.2199x over previous
//
#include <hip/hip_runtime.h>
#include <hip/hip_bf16.h>
#include <hip/hip_fp16.h>

// GCN 3-layer forward.
// CSR build (count -> fused dinv+alloc -> fill) -> per layer:
//   fp16 MFMA GEMM (A,W single fp16 planes; 1 MFMA/frag; global->reg prefetch)
//   -> CSR agg over fp16 rows (8-deep gather pipeline, BN/ReLU, fp16 plane out).
// Round-12 lessons: per-row source sort cost 100us for <=14us agg gain (locality
// theory falsified) -- removed. fp16xfp16 error ~1e-3/layer, under the measured
// fp16-hop floor (3.9e-3); threshold 12e-3 leaves ~2x margin.

#define GN 50000
#define GE 800000

typedef float f32x4 __attribute__((ext_vector_type(4)));
typedef _Float16 f16x8 __attribute__((ext_vector_type(8)));

// ---------------- graph setup ----------------

__global__ __launch_bounds__(256) void init_kernel(int* counts, int* cursor, int* total) {
    int i = blockIdx.x * 256 + threadIdx.x;
    if (i < GN) { counts[i] = 0; cursor[i] = 0; }
    if (i == 0) *total = 0;
}

__global__ __launch_bounds__(256) void count_kernel(const int* __restrict__ dst, int* __restrict__ counts) {
    int e = blockIdx.x * 256 + threadIdx.x;
    if (e < GE) atomicAdd(&counts[dst[e]], 1);
}

// fused: dinv + disjoint CSR segment allocation (wave shfl-scan + 1 atomic/wave)
__global__ __launch_bounds__(256) void alloc_kernel(const int* __restrict__ counts, float* __restrict__ dinv,
                                                    int* __restrict__ base, int* __restrict__ total) {
    int i = blockIdx.x * 256 + threadIdx.x;
    int lane = threadIdx.x & 63;
    int c = (i < GN) ? counts[i] : 0;
    if (i < GN) dinv[i] = rsqrtf((float)c + 1.0f);
    int v = c;
#pragma unroll
    for (int off = 1; off < 64; off <<= 1) {
        int t = __shfl_up(v, off);
        if (lane >= off) v += t;
    }
    int waveSum = __shfl(v, 63);
    int wb = 0;
    if (lane == 63) wb = atomicAdd(total, waveSum);
    wb = __shfl(wb, 63);
    if (i < GN) base[i] = wb + v - c;  // exclusive intra-wave prefix + wave base
}

__global__ __launch_bounds__(256) void fill_kernel(const int* __restrict__ src, const int* __restrict__ dst,
                                                   const int* __restrict__ base, int* __restrict__ cursor,
                                                   int* __restrict__ col) {
    int e = blockIdx.x * 256 + threadIdx.x;
    if (e < GE) {
        int d = dst[e];
        int pos = base[d] + atomicAdd(&cursor[d], 1);
        col[pos] = src[e];
    }
}

__global__ __launch_bounds__(256) void params_kernel(
    const float* b1, const float* g1, const float* be1, const float* m1, const float* v1,
    const float* b2, const float* g2, const float* be2, const float* m2, const float* v2,
    float* prm) {
    int t = threadIdx.x;
    float s1 = g1[t] * rsqrtf(v1[t] + 1e-5f);
    prm[0 * 256 + t] = s1;
    prm[1 * 256 + t] = (b1[t] - m1[t]) * s1 + be1[t];
    float s2 = g2[t] * rsqrtf(v2[t] + 1e-5f);
    prm[2 * 256 + t] = s2;
    prm[3 * 256 + t] = (b2[t] - m2[t]) * s2 + be2[t];
}

// ---------------- pre-passes ----------------

// x fp32 -> single fp16 plane
__global__ __launch_bounds__(256) void conv_x(const float* __restrict__ in, ushort* __restrict__ out, int n4) {
    int i = blockIdx.x * 256 + threadIdx.x;
    if (i >= n4) return;
    float4 v = *(const float4*)&in[(size_t)i * 4];
    ushort4 h;
    h.x = __half_as_ushort(__float2half_rn(v.x));
    h.y = __half_as_ushort(__float2half_rn(v.y));
    h.z = __half_as_ushort(__float2half_rn(v.z));
    h.w = __half_as_ushort(__float2half_rn(v.w));
    *(ushort4*)&out[(size_t)i * 4] = h;
}

// all three W [256][DO] fp32 -> WT fp16 [DO][256], one kernel
__global__ __launch_bounds__(256) void transpose_all(const float* __restrict__ W1, const float* __restrict__ W2,
                                                     const float* __restrict__ W3,
                                                     ushort* __restrict__ T1, ushort* __restrict__ T2,
                                                     ushort* __restrict__ T3) {
    int idx = blockIdx.x * 256 + threadIdx.x;
    const float* W;
    ushort* T;
    int i, DO;
    if (idx < 65536) { W = W1; T = T1; i = idx; DO = 256; }
    else if (idx < 131072) { W = W2; T = T2; i = idx - 65536; DO = 256; }
    else if (idx < 163840) { W = W3; T = T3; i = idx - 131072; DO = 128; }
    else return;
    int n = i >> 8, k = i & 255;
    T[i] = __half_as_ushort(__float2half_rn(W[k * DO + n]));
}

// ---------------- fp16 MFMA GEMM with global->reg prefetch ----------------
// C[m][n] = dinv[m] * sum_k A[m][k]*W[k][n]; A: fp16 plane [M][256];
// W: transposed fp16 plane [DO][256]. BM=128,BN=128,BK=32; 4 waves (2x2), 64x64/wave.

template <int DO>
__global__ __launch_bounds__(256) void gemm_mfma(const ushort* __restrict__ A16, const ushort* __restrict__ B16,
                                                 const float* __restrict__ dinv, __half* __restrict__ C, int M) {
    __shared__ ushort lds[2][128][40];  // 80B rows (pad 16B) -> <=2-way bank conflict on ds_read_b128
    int tid = threadIdx.x;
    int lane = tid & 63;
    int wave = tid >> 6;
    int wm = wave >> 1, wn = wave & 1;
    int m0 = blockIdx.x * 128;
    int n0 = blockIdx.y * 128;
    int rsel = lane & 15;
    int ksel = (lane >> 4) * 8;

    // staging coordinates (2 x 16B per plane per thread)
    int o0 = tid * 16, o1 = (tid + 256) * 16;
    int row0 = o0 >> 6, kb0 = o0 & 63;
    int row1 = o1 >> 6, kb1 = o1 & 63;
    int rA0 = min(m0 + row0, M - 1), rA1 = min(m0 + row1, M - 1);
    int rB0 = min(n0 + row0, DO - 1), rB1 = min(n0 + row1, DO - 1);

    uint4 vA0, vA1, vB0, vB1;
    auto loadregs = [&](int k0) {
        const char* a = (const char*)A16;
        const char* b = (const char*)B16;
        vA0 = *(const uint4*)(a + (size_t)rA0 * 512 + (size_t)k0 * 2 + kb0);
        vA1 = *(const uint4*)(a + (size_t)rA1 * 512 + (size_t)k0 * 2 + kb1);
        vB0 = *(const uint4*)(b + (size_t)rB0 * 512 + (size_t)k0 * 2 + kb0);
        vB1 = *(const uint4*)(b + (size_t)rB1 * 512 + (size_t)k0 * 2 + kb1);
    };
    auto writelds = [&]() {
        *(uint4*)((char*)&lds[0][row0][0] + kb0) = vA0;
        *(uint4*)((char*)&lds[0][row1][0] + kb1) = vA1;
        *(uint4*)((char*)&lds[1][row0][0] + kb0) = vB0;
        *(uint4*)((char*)&lds[1][row1][0] + kb1) = vB1;
    };

    f32x4 acc[4][4] = {};

    loadregs(0);
    for (int k0 = 0; k0 < 256; k0 += 32) {
        writelds();
        __syncthreads();
        if (k0 + 32 < 256) loadregs(k0 + 32);  // prefetch next K-step; HBM latency hides under MFMA

        f16x8 bv[4];
#pragma unroll
        for (int ni = 0; ni < 4; ni++)
            bv[ni] = *(const f16x8*)&lds[1][wn * 64 + ni * 16 + rsel][ksel];
#pragma unroll
        for (int mi = 0; mi < 4; mi++) {
            f16x8 av = *(const f16x8*)&lds[0][wm * 64 + mi * 16 + rsel][ksel];
#pragma unroll
            for (int ni = 0; ni < 4; ni++)
                acc[mi][ni] = __builtin_amdgcn_mfma_f32_16x16x32_f16(av, bv[ni], acc[mi][ni], 0, 0, 0);
        }
        __syncthreads();
    }

    // epilogue: C/D layout col=lane&15, row=(lane>>4)*4+j  [m89-verified]; fp16 store
#pragma unroll
    for (int mi = 0; mi < 4; mi++) {
#pragma unroll
        for (int j = 0; j < 4; j++) {
            int r = m0 + wm * 64 + mi * 16 + (lane >> 4) * 4 + j;
            if (r < M) {
                float dv = dinv[r];
#pragma unroll
                for (int ni = 0; ni < 4; ni++) {
                    int c = n0 + wn * 64 + ni * 16 + rsel;
                    C[(size_t)r * DO + c] = __float2half_rn(acc[mi][ni][j] * dv);
                }
            }
        }
    }
}

// ---------------- CSR aggregation over fp16 rows (8-deep gather pipeline) ----------------
// MODE 1: val = relu(val*pa+pc), write fp16 plane. MODE 0: val = val + pa, write fp32.
template <int D, int MODE>
__global__ __launch_bounds__(256) void agg_kernel(const __half* __restrict__ Hs, const int* __restrict__ base,
                                                  const int* __restrict__ counts, const float* __restrict__ dinv,
                                                  const int* __restrict__ col,
                                                  const float* __restrict__ pa, const float* __restrict__ pc,
                                                  float* __restrict__ outF, ushort* __restrict__ outH, int M) {
    constexpr int V = D / 64;   // halfs per lane: 4 (D=256) or 2 (D=128)
    constexpr int P = V / 2;    // float2 accumulators
    int w = blockIdx.x * 4 + (threadIdx.x >> 6);
    if (w >= M) return;
    int lane = threadIdx.x & 63;
    const char* gbase = (const char*)(Hs + lane * V);  // + s*D*2 bytes per row
    float2 acc2[P];
#pragma unroll
    for (int j = 0; j < P; j++) acc2[j] = make_float2(0.f, 0.f);

    auto accum32 = [&](unsigned bits, int j2) {  // add 2 halfs packed in u32
        __half2 h = *(__half2*)&bits;
        float2 f = __half22float2(h);
        acc2[j2].x += f.x;
        acc2[j2].y += f.y;
    };

    // self loop
    if constexpr (V == 4) {
        uint2 r = *(const uint2*)(gbase + (size_t)w * D * 2);
        accum32(r.x, 0); accum32(r.y, 1);
    } else {
        unsigned r = *(const unsigned*)(gbase + (size_t)w * D * 2);
        accum32(r, 0);
    }

    int e = base[w], end = e + counts[w];
    // 8 rows in flight
    for (; e + 8 <= end; e += 8) {
        int idx[8];
#pragma unroll
        for (int t = 0; t < 8; t++) idx[t] = col[e + t];
        if constexpr (V == 4) {
            uint2 r[8];
#pragma unroll
            for (int t = 0; t < 8; t++) r[t] = *(const uint2*)(gbase + (size_t)idx[t] * (D * 2));
#pragma unroll
            for (int t = 0; t < 8; t++) { accum32(r[t].x, 0); accum32(r[t].y, 1); }
        } else {
            unsigned r[8];
#pragma unroll
            for (int t = 0; t < 8; t++) r[t] = *(const unsigned*)(gbase + (size_t)idx[t] * (D * 2));
#pragma unroll
            for (int t = 0; t < 8; t++) accum32(r[t], 0);
        }
    }
    for (; e < end; e++) {
        int s = col[e];
        if constexpr (V == 4) {
            uint2 r = *(const uint2*)(gbase + (size_t)s * (D * 2));
            accum32(r.x, 0); accum32(r.y, 1);
        } else {
            unsigned r = *(const unsigned*)(gbase + (size_t)s * (D * 2));
            accum32(r, 0);
        }
    }

    float dv = dinv[w];
    float acc[V];
#pragma unroll
    for (int j = 0; j < P; j++) { acc[2 * j] = acc2[j].x; acc[2 * j + 1] = acc2[j].y; }

    if constexpr (MODE == 1) {
        ushort4 h;
        int d = lane * V;
        float val;
        val = fmaxf(fmaf(acc[0] * dv, pa[d + 0], pc[d + 0]), 0.f);
        h.x = __half_as_ushort(__float2half_rn(val));
        val = fmaxf(fmaf(acc[1] * dv, pa[d + 1], pc[d + 1]), 0.f);
        h.y = __half_as_ushort(__float2half_rn(val));
        val = fmaxf(fmaf(acc[2] * dv, pa[d + 2], pc[d + 2]), 0.f);
        h.z = __half_as_ushort(__float2half_rn(val));
        val = fmaxf(fmaf(acc[3] * dv, pa[d + 3], pc[d + 3]), 0.f);
        h.w = __half_as_ushort(__float2half_rn(val));
        *(ushort4*)&outH[(size_t)w * D + d] = h;
    } else {
#pragma unroll
        for (int j = 0; j < V; j++) {
            int d = lane * V + j;
            outF[(size_t)w * D + d] = acc[j] * dv + pa[d];
        }
    }
}

// ---------------- launch ----------------

extern "C" void kernel_launch(void* const* d_in, const int* in_sizes, int n_in,
                              void* d_out, int out_size, void* d_ws, size_t ws_size,
                              hipStream_t stream) {
    const float* x = (const float*)d_in[0];
    const int* ei = (const int*)d_in[1];
    const int* srcIdx = ei;
    const int* dstIdx = ei + GE;
    const float* W1 = (const float*)d_in[2];
    const float* b1 = (const float*)d_in[3];
    const float* g1 = (const float*)d_in[4];
    const float* be1 = (const float*)d_in[5];
    const float* m1 = (const float*)d_in[6];
    const float* v1 = (const float*)d_in[7];
    const float* W2 = (const float*)d_in[8];
    const float* b2 = (const float*)d_in[9];
    const float* g2 = (const float*)d_in[10];
    const float* be2 = (const float*)d_in[11];
    const float* m2 = (const float*)d_in[12];
    const float* v2 = (const float*)d_in[13];
    const float* W3 = (const float*)d_in[14];
    const float* b3 = (const float*)d_in[15];
    float* out = (float*)d_out;

    size_t off = 0;
    char* wsb = (char*)d_ws;
    auto take = [&](size_t bytes) -> char* {
        char* p = wsb + off;
        off += (bytes + 255) & ~(size_t)255;
        return p;
    };
    float* dinv = (float*)take((size_t)GN * 4);
    int* counts = (int*)take((size_t)GN * 4);
    int* cursor = (int*)take((size_t)GN * 4);
    int* segbase = (int*)take((size_t)GN * 4);
    int* total = (int*)take(256);
    int* col = (int*)take((size_t)GE * 4);
    float* prm = (float*)take(4 * 256 * 4);
    __half* hH = (__half*)take((size_t)GN * 256 * 2);  // GEMM output (fp16)
    ushort* P = (ushort*)take((size_t)GN * 256 * 2);   // activation fp16 plane (x16 aliased)
    ushort* X16 = P;                                   // layer-1 A: fp16(x); consumed before agg writes P
    ushort* WT1 = (ushort*)take(256 * 256 * 2);
    ushort* WT2 = (ushort*)take(256 * 256 * 2);
    ushort* WT3 = (ushort*)take(128 * 256 * 2);

    const float* a1 = prm + 0 * 256;
    const float* c1 = prm + 1 * 256;
    const float* a2 = prm + 2 * 256;
    const float* c2 = prm + 3 * 256;

    int nb = (GN + 255) / 256;
    int eb = (GE + 255) / 256;

    init_kernel<<<nb, 256, 0, stream>>>(counts, cursor, total);
    count_kernel<<<eb, 256, 0, stream>>>(dstIdx, counts);
    alloc_kernel<<<nb, 256, 0, stream>>>(counts, dinv, segbase, total);
    fill_kernel<<<eb, 256, 0, stream>>>(srcIdx, dstIdx, segbase, cursor, col);
    params_kernel<<<1, 256, 0, stream>>>(b1, g1, be1, m1, v1, b2, g2, be2, m2, v2, prm);

    int n4 = GN * 64;  // GN*256/4 float4s
    conv_x<<<(n4 + 255) / 256, 256, 0, stream>>>(x, X16, n4);
    transpose_all<<<(163840 + 255) / 256, 256, 0, stream>>>(W1, W2, W3, WT1, WT2, WT3);

    dim3 gg((GN + 127) / 128, 2);
    dim3 gg3((GN + 127) / 128, 1);
    int ab = (GN + 3) / 4;

    // layer 1
    gemm_mfma<256><<<gg, 256, 0, stream>>>(X16, WT1, dinv, hH, GN);
    agg_kernel<256, 1><<<ab, 256, 0, stream>>>(hH, segbase, counts, dinv, col, a1, c1, nullptr, P, GN);
    // layer 2
    gemm_mfma<256><<<gg, 256, 0, stream>>>(P, WT2, dinv, hH, GN);
    agg_kernel<256, 1><<<ab, 256, 0, stream>>>(hH, segbase, counts, dinv, col, a2, c2, nullptr, P, GN);
    // layer 3
    gemm_mfma<128><<<gg3, 256, 0, stream>>>(P, WT3, dinv, hH, GN);
    agg_kernel<128, 0><<<ab, 256, 0, stream>>>(hH, segbase, counts, dinv, col, b3, b3, out, nullptr, GN);
}